// Round 9
// baseline (360.063 us; speedup 1.0000x reference)
//
#include <hip/hip_runtime.h>

#define IN_DIM 18
#define XPAD 20     // IN_DIM padded to float4 multiple (5 slots)
#define HID 64
#define EMB 32
#define NGROUP 8    // legacy fallback partitioning
#define PSHIFT 9    // 512 nodes per partition
#define PMAX 200    // LDS arrays sized for <=200 partitions (N<=102400)
#define BCAP 40     // k_part per-tile LDS bin capacity (mean ~21 @ TILE 4096)
#define TILE 4096

typedef int vint4 __attribute__((ext_vector_type(4)));
typedef unsigned long long u64;

__device__ inline float4 shfl_f4(float4 v, int srcLane) {
    float4 r;
    r.x = __shfl(v.x, srcLane);
    r.y = __shfl(v.y, srcLane);
    r.z = __shfl(v.z, srcLane);
    r.w = __shfl(v.w, srcLane);
    return r;
}

__device__ inline float4 shfl_xor_f4(float4 v, int m) {
    v.x = __shfl_xor(v.x, m);
    v.y = __shfl_xor(v.y, m);
    v.z = __shfl_xor(v.z, m);
    v.w = __shfl_xor(v.w, m);
    return v;
}

// ---------------- init ----------------

__global__ void k_init(int* __restrict__ deg, int* __restrict__ gcnt, int n) {
    int i = blockIdx.x * 256 + threadIdx.x;
    if (i < n) deg[i] = 1;          // legacy path
    if (i < 256) gcnt[i] = 0;
}

// ---------------- bucketing: (dst,src) -> P dst-partition buckets ----------
// pair packed as u64: (src<<32) | dst

__global__ void k_part(const int* __restrict__ src, const int* __restrict__ dst,
                       int* __restrict__ gcnt, u64* __restrict__ gbuf,
                       int e, int Pp, int cap) {
    __shared__ u64 sbuf[PMAX][BCAP];
    __shared__ int scnt[PMAX];
    __shared__ int sbase[PMAX];
    int tid = threadIdx.x;
    int ntile = (e + TILE - 1) / TILE;
    for (int tile = blockIdx.x; tile < ntile; tile += gridDim.x) {
        for (int p = tid; p < Pp; p += 256) scnt[p] = 0;
        __syncthreads();
#pragma unroll
        for (int r = 0; r < TILE / 1024; ++r) {
            int i = tile * TILE + (r * 256 + tid) * 4;
            if (i + 4 <= e) {
                vint4 s4 = __builtin_nontemporal_load((const vint4*)(src + i));
                vint4 d4 = __builtin_nontemporal_load((const vint4*)(dst + i));
#pragma unroll
                for (int k = 0; k < 4; ++k) {
                    int d = d4[k];
                    int p = d >> PSHIFT;
                    u64 pr = ((u64)(unsigned)s4[k] << 32) | (unsigned)d;
                    int pos = atomicAdd(&scnt[p], 1);
                    if (pos < BCAP) sbuf[p][pos] = pr;
                    else {
                        int gp = atomicAdd(&gcnt[p], 1);
                        __builtin_nontemporal_store(pr, &gbuf[(size_t)p * cap + gp]);
                    }
                }
            } else if (i < e) {
                for (int k = i; k < e; ++k) {
                    int d = dst[k];
                    int p = d >> PSHIFT;
                    u64 pr = ((u64)(unsigned)src[k] << 32) | (unsigned)d;
                    int pos = atomicAdd(&scnt[p], 1);
                    if (pos < BCAP) sbuf[p][pos] = pr;
                    else {
                        int gp = atomicAdd(&gcnt[p], 1);
                        __builtin_nontemporal_store(pr, &gbuf[(size_t)p * cap + gp]);
                    }
                }
            }
        }
        __syncthreads();
        for (int p = tid; p < Pp; p += 256)
            sbase[p] = atomicAdd(&gcnt[p], min(scnt[p], BCAP));
        __syncthreads();
        int wid = tid >> 6, lane = tid & 63;
        for (int p = wid; p < Pp; p += 4) {
            int c = min(scnt[p], BCAP);
            int b = sbase[p];
            for (int k = lane; k < c; k += 64)
                __builtin_nontemporal_store(sbuf[p][k], &gbuf[(size_t)p * cap + b + k]);
        }
        __syncthreads();
    }
}

// ---------------- tiny exclusive scan of bucket counts ----------------

__global__ void k_gscan(const int* __restrict__ gcnt, int* __restrict__ gbase, int Pp) {
    __shared__ int s[256];
    int t = threadIdx.x;
    int v = (t < Pp) ? gcnt[t] : 0;
    s[t] = v;
    __syncthreads();
    for (int off = 1; off < 256; off <<= 1) {
        int u = (t >= off) ? s[t - off] : 0;
        __syncthreads();
        s[t] += u;
        __syncthreads();
    }
    if (t < Pp) gbase[t] = s[t] - v;
}

// ---------------- per-partition build, 3-way src-chunk segmented CSR --------
// adj per node laid out as [chunk0 srcs][chunk1 srcs][chunk2 srcs];
// boundaries row_ptr/m1/m2/mend enable phase-coherent chunked aggregation.

__global__ void k_build3(const u64* __restrict__ gbuf, const int* __restrict__ gcnt,
                         const int* __restrict__ gbase, int* __restrict__ deg,
                         float* __restrict__ dis, int* __restrict__ row_ptr,
                         int* __restrict__ m1, int* __restrict__ m2,
                         int* __restrict__ mend, int* __restrict__ adj,
                         int cap, int n, int c1, int c2) {
    __shared__ int sdeg[3][512];
    __shared__ int sstart[3][512];
    __shared__ int swp[3][512];
    __shared__ int sscan[512];
    int p = blockIdx.x;
    int tid = threadIdx.x;   // 512 threads
    int lo = p << PSHIFT;
    int nn = min(n - lo, 512);
    int cnt = gcnt[p];
    int base = gbase[p];
    const u64* buf = gbuf + (size_t)p * cap;

    sdeg[0][tid] = 0; sdeg[1][tid] = 0; sdeg[2][tid] = 0;
    __syncthreads();
    for (int k = tid; k < cnt; k += 512) {
        u64 pr = __builtin_nontemporal_load(&buf[k]);
        int dl = (int)(pr & 0xffffffffu) - lo;
        int s = (int)(pr >> 32);
        int c = (s >= c1) + (s >= c2);
        atomicAdd(&sdeg[c][dl], 1);
    }
    __syncthreads();
    int t0 = sdeg[0][tid], t1 = sdeg[1][tid], t2 = sdeg[2][tid];
    int tot = t0 + t1 + t2;
    sscan[tid] = tot;
    __syncthreads();
    for (int off = 1; off < 512; off <<= 1) {
        int u = (tid >= off) ? sscan[tid - off] : 0;
        __syncthreads();
        sscan[tid] += u;
        __syncthreads();
    }
    int excl = sscan[tid] - tot;
    sstart[0][tid] = excl;
    sstart[1][tid] = excl + t0;
    sstart[2][tid] = excl + t0 + t1;
    swp[0][tid] = 0; swp[1][tid] = 0; swp[2][tid] = 0;
    __syncthreads();
    if (tid < nn) {
        int dg = tot + 1;
        deg[lo + tid] = dg;
        dis[lo + tid] = rsqrtf((float)dg);
        row_ptr[lo + tid] = base + excl;
        m1[lo + tid]  = base + sstart[1][tid];
        m2[lo + tid]  = base + sstart[2][tid];
        mend[lo + tid] = base + excl + tot;
    }
    for (int k = tid; k < cnt; k += 512) {
        u64 pr = __builtin_nontemporal_load(&buf[k]);
        int dl = (int)(pr & 0xffffffffu) - lo;
        int s = (int)(pr >> 32);
        int c = (s >= c1) + (s >= c2);
        int slot = sstart[c][dl] + atomicAdd(&swp[c][dl], 1);
        adj[base + slot] = s;
    }
}

// ---------------- legacy fallback ----------------

__global__ void k_count_part(const int* __restrict__ dst, int* __restrict__ deg,
                             int e, int nrange, int n) {
    int g  = blockIdx.x & (NGROUP - 1);
    int lo = g * nrange;
    int hi = min(n, lo + nrange);
    int bid  = blockIdx.x >> 3;
    int nblk = gridDim.x >> 3;
    int i0   = (bid * 256 + threadIdx.x) * 4;
    int step = nblk * 256 * 4;
    for (int i = i0; i < e; i += step) {
        if (i + 4 <= e) {
            int4 d4 = *(const int4*)(dst + i);
            if (d4.x >= lo && d4.x < hi) atomicAdd(&deg[d4.x], 1);
            if (d4.y >= lo && d4.y < hi) atomicAdd(&deg[d4.y], 1);
            if (d4.z >= lo && d4.z < hi) atomicAdd(&deg[d4.z], 1);
            if (d4.w >= lo && d4.w < hi) atomicAdd(&deg[d4.w], 1);
        } else {
            for (int k = i; k < e; ++k) {
                int d = dst[k];
                if (d >= lo && d < hi) atomicAdd(&deg[d], 1);
            }
        }
    }
}

__global__ void k_dis(const int* __restrict__ deg, float* __restrict__ dis, int n) {
    int i = blockIdx.x * 256 + threadIdx.x;
    if (i < n) dis[i] = rsqrtf((float)deg[i]);
}

__global__ void k_scanA(const int* __restrict__ deg, int* __restrict__ row_ptr,
                        int* __restrict__ blksums, int n) {
    __shared__ int s[1024];
    int tid = threadIdx.x;
    int i = blockIdx.x * 1024 + tid;
    int v = (i < n) ? (deg[i] - 1) : 0;
    s[tid] = v;
    __syncthreads();
    for (int off = 1; off < 1024; off <<= 1) {
        int t = (tid >= off) ? s[tid - off] : 0;
        __syncthreads();
        s[tid] += t;
        __syncthreads();
    }
    if (i < n) row_ptr[i] = s[tid] - v;
    if (tid == 1023) blksums[blockIdx.x] = s[1023];
}

__global__ void k_scanB(const int* __restrict__ blksums, int* __restrict__ blkoffs, int nb) {
    __shared__ int s[1024];
    int tid = threadIdx.x;
    int v = (tid < nb) ? blksums[tid] : 0;
    s[tid] = v;
    __syncthreads();
    for (int off = 1; off < 1024; off <<= 1) {
        int t = (tid >= off) ? s[tid - off] : 0;
        __syncthreads();
        s[tid] += t;
        __syncthreads();
    }
    if (tid < nb) blkoffs[tid] = s[tid] - v;
}

__global__ void k_scanC(int* __restrict__ row_ptr, const int* __restrict__ blkoffs,
                        int* __restrict__ write_ptr, int n) {
    int i = blockIdx.x * 1024 + threadIdx.x;
    if (i < n) {
        int r = row_ptr[i] + blkoffs[blockIdx.x];
        row_ptr[i] = r;
        write_ptr[i] = r;
    }
}

__global__ void k_fill_part(const int* __restrict__ src, const int* __restrict__ dst,
                            int* __restrict__ write_ptr, int* __restrict__ adj,
                            int e, int nrange, int n) {
    int g  = blockIdx.x & (NGROUP - 1);
    int lo = g * nrange;
    int hi = min(n, lo + nrange);
    int bid  = blockIdx.x >> 3;
    int nblk = gridDim.x >> 3;
    int i0   = (bid * 256 + threadIdx.x) * 4;
    int step = nblk * 256 * 4;
    for (int i = i0; i < e; i += step) {
        if (i + 4 <= e) {
            int4 d4 = *(const int4*)(dst + i);
            if (d4.x >= lo && d4.x < hi) { int slot = atomicAdd(&write_ptr[d4.x], 1); adj[slot] = src[i];     }
            if (d4.y >= lo && d4.y < hi) { int slot = atomicAdd(&write_ptr[d4.y], 1); adj[slot] = src[i + 1]; }
            if (d4.z >= lo && d4.z < hi) { int slot = atomicAdd(&write_ptr[d4.z], 1); adj[slot] = src[i + 2]; }
            if (d4.w >= lo && d4.w < hi) { int slot = atomicAdd(&write_ptr[d4.w], 1); adj[slot] = src[i + 3]; }
        } else {
            for (int k = i; k < e; ++k) {
                int d = dst[k];
                if (d >= lo && d < hi) { int slot = atomicAdd(&write_ptr[d], 1); adj[slot] = src[k]; }
            }
        }
    }
}

__global__ void k_mend(const int* __restrict__ row_ptr, const int* __restrict__ deg,
                       int* __restrict__ mend, int n) {
    int i = blockIdx.x * 256 + threadIdx.x;
    if (i < n) mend[i] = row_ptr[i] + deg[i] - 1;
}

// ---------------- xn = x * dis, padded to 20 floats ----------------

__global__ void k_xn(const float* __restrict__ x, const float* __restrict__ dis,
                     float* __restrict__ xn, int n) {
    int gid = blockIdx.x * 256 + threadIdx.x;
    if (gid >= n * 5) return;
    int i = gid / 5, s = gid - (gid / 5) * 5;
    float dn = dis[i];
    const float* xr = x + (size_t)i * IN_DIM;
    float4 v;
    int k = s * 4;
    v.x = (k + 0 < IN_DIM) ? xr[k + 0] * dn : 0.f;
    v.y = (k + 1 < IN_DIM) ? xr[k + 1] * dn : 0.f;
    v.z = (k + 2 < IN_DIM) ? xr[k + 2] * dn : 0.f;
    v.w = (k + 3 < IN_DIM) ? xr[k + 3] * dn : 0.f;
    *(float4*)(xn + (size_t)i * XPAD + k) = v;
}

// ---------------- agg1 partial pass (lean, no weights) ----------------
// Wave per node; gathers xn rows for adj[lo,hi) (one src chunk; L2-resident),
// 12 edge-groups x 5 lanes x float4, x2 unroll. mode1 = accumulate into agg.

__global__ void k_agg1p(const float* __restrict__ xn, const int* __restrict__ adj,
                        const int* __restrict__ lo, const int* __restrict__ hi,
                        float* __restrict__ agg, int n, int mode) {
    int node = blockIdx.x * 4 + (threadIdx.x >> 6);
    if (node >= n) return;
    int lane = threadIdx.x & 63;
    int eg = lane / 5;
    int sl = lane - eg * 5;
    bool act = eg < 12;
    int beg = lo[node];
    int cnt = hi[node] - beg;
    const int* a = adj + beg;
    float4 acc = make_float4(0.f, 0.f, 0.f, 0.f);
    int base = 0;
    for (; base + 24 <= cnt; base += 24) {
        if (act) {
            int j0 = a[base + eg];
            int j1 = a[base + 12 + eg];
            float4 v0 = *(const float4*)(xn + (size_t)j0 * XPAD + sl * 4);
            float4 v1 = *(const float4*)(xn + (size_t)j1 * XPAD + sl * 4);
            acc.x += v0.x + v1.x; acc.y += v0.y + v1.y;
            acc.z += v0.z + v1.z; acc.w += v0.w + v1.w;
        }
    }
    if (act && base + eg < cnt) {
        float4 v = *(const float4*)(xn + (size_t)a[base + eg] * XPAD + sl * 4);
        acc.x += v.x; acc.y += v.y; acc.z += v.z; acc.w += v.w;
    }
    if (act && base + 12 + eg < cnt) {
        float4 v = *(const float4*)(xn + (size_t)a[base + 12 + eg] * XPAD + sl * 4);
        acc.x += v.x; acc.y += v.y; acc.z += v.z; acc.w += v.w;
    }
    float4 t = shfl_f4(acc, lane + 30);
    if (lane < 30) { acc.x += t.x; acc.y += t.y; acc.z += t.z; acc.w += t.w; }
    t = shfl_f4(acc, lane + 15);
    if (lane < 15) { acc.x += t.x; acc.y += t.y; acc.z += t.z; acc.w += t.w; }
    t = shfl_f4(acc, lane + 10);
    if (lane < 5) { acc.x += t.x; acc.y += t.y; acc.z += t.z; acc.w += t.w; }
    t = shfl_f4(acc, lane + 5);
    if (lane < 5) { acc.x += t.x; acc.y += t.y; acc.z += t.z; acc.w += t.w; }
    if (lane < 5) {
        float* dp = agg + (size_t)node * XPAD + lane * 4;
        if (mode) {
            float4 old = *(float4*)dp;
            acc.x += old.x; acc.y += old.y; acc.z += old.z; acc.w += old.w;
        }
        *(float4*)dp = acc;
    }
}

// ---------------- agg1 final: last chunk + combine + W1 + relu + W2 ---------

__global__ void k_agg1z(const float* __restrict__ xn, const int* __restrict__ adj,
                        const int* __restrict__ lo, const int* __restrict__ hi,
                        const float* __restrict__ agg, const float* __restrict__ dis,
                        const float* __restrict__ W1, const float* __restrict__ b1,
                        const float* __restrict__ W2, float* __restrict__ hn2, int n) {
    __shared__ float sw[IN_DIM * HID];
    __shared__ float sw2[HID * EMB];
    __shared__ float sb[HID];
    __shared__ __align__(16) float sagg[4][XPAD];
    __shared__ float sh[4][HID];
    int tid = threadIdx.x;
    for (int t = tid; t < IN_DIM * HID; t += 256) sw[t] = W1[t];
    for (int t = tid; t < HID * EMB; t += 256) sw2[t] = W2[t];
    if (tid < HID) sb[tid] = b1[tid];
    __syncthreads();
    int node = blockIdx.x * 4 + (tid >> 6);
    if (node >= n) return;
    int lane = tid & 63;
    int wv = tid >> 6;
    int eg = lane / 5;
    int sl = lane - eg * 5;
    bool act = eg < 12;
    int beg = lo[node];
    int cnt = hi[node] - beg;
    const int* a = adj + beg;
    float4 acc = make_float4(0.f, 0.f, 0.f, 0.f);
    int base = 0;
    for (; base + 24 <= cnt; base += 24) {
        if (act) {
            int j0 = a[base + eg];
            int j1 = a[base + 12 + eg];
            float4 v0 = *(const float4*)(xn + (size_t)j0 * XPAD + sl * 4);
            float4 v1 = *(const float4*)(xn + (size_t)j1 * XPAD + sl * 4);
            acc.x += v0.x + v1.x; acc.y += v0.y + v1.y;
            acc.z += v0.z + v1.z; acc.w += v0.w + v1.w;
        }
    }
    if (act && base + eg < cnt) {
        float4 v = *(const float4*)(xn + (size_t)a[base + eg] * XPAD + sl * 4);
        acc.x += v.x; acc.y += v.y; acc.z += v.z; acc.w += v.w;
    }
    if (act && base + 12 + eg < cnt) {
        float4 v = *(const float4*)(xn + (size_t)a[base + 12 + eg] * XPAD + sl * 4);
        acc.x += v.x; acc.y += v.y; acc.z += v.z; acc.w += v.w;
    }
    float4 t = shfl_f4(acc, lane + 30);
    if (lane < 30) { acc.x += t.x; acc.y += t.y; acc.z += t.z; acc.w += t.w; }
    t = shfl_f4(acc, lane + 15);
    if (lane < 15) { acc.x += t.x; acc.y += t.y; acc.z += t.z; acc.w += t.w; }
    t = shfl_f4(acc, lane + 10);
    if (lane < 5) { acc.x += t.x; acc.y += t.y; acc.z += t.z; acc.w += t.w; }
    t = shfl_f4(acc, lane + 5);
    if (lane < 5) { acc.x += t.x; acc.y += t.y; acc.z += t.z; acc.w += t.w; }
    float dn = dis[node];
    if (lane < 5) {
        float4 pp = *(const float4*)(agg + (size_t)node * XPAD + lane * 4);
        float4 s4v = *(const float4*)(xn + (size_t)node * XPAD + lane * 4);
        acc.x += pp.x + s4v.x; acc.y += pp.y + s4v.y;
        acc.z += pp.z + s4v.z; acc.w += pp.w + s4v.w;
        *(float4*)&sagg[wv][lane * 4] = acc;   // same-wave LDS
    }
    float s = 0.f;
#pragma unroll
    for (int k = 0; k < IN_DIM; ++k) s += sagg[wv][k] * sw[k * HID + lane];
    float hv = dn * s + sb[lane];
    sh[wv][lane] = hv > 0.f ? hv : 0.f;
    int g = lane & 31, half = lane >> 5;
    float s2 = 0.f;
#pragma unroll
    for (int k = 0; k < 32; ++k) s2 += sh[wv][half * 32 + k] * sw2[(half * 32 + k) * EMB + g];
    s2 += __shfl_xor(s2, 32);
    if (half == 0) hn2[(size_t)node * EMB + g] = dn * s2;
}

// ---------------- agg2 partial pass ----------------

__global__ void k_agg2p(const float* __restrict__ hn2, const int* __restrict__ adj,
                        const int* __restrict__ lo, const int* __restrict__ hi,
                        float* __restrict__ z, int n, int mode) {
    int node = blockIdx.x * 4 + (threadIdx.x >> 6);
    if (node >= n) return;
    int lane = threadIdx.x & 63;
    int eg = lane >> 3;
    int d4 = lane & 7;
    int beg = lo[node];
    int cnt = hi[node] - beg;
    const int* a = adj + beg;
    float4 acc = make_float4(0.f, 0.f, 0.f, 0.f);
    int base = 0;
    for (; base + 24 <= cnt; base += 24) {
        int j0 = a[base + eg];
        int j1 = a[base + 8 + eg];
        int j2 = a[base + 16 + eg];
        float4 v0 = *(const float4*)(hn2 + (size_t)j0 * EMB + d4 * 4);
        float4 v1 = *(const float4*)(hn2 + (size_t)j1 * EMB + d4 * 4);
        float4 v2 = *(const float4*)(hn2 + (size_t)j2 * EMB + d4 * 4);
        acc.x += v0.x + v1.x + v2.x; acc.y += v0.y + v1.y + v2.y;
        acc.z += v0.z + v1.z + v2.z; acc.w += v0.w + v1.w + v2.w;
    }
    int kk = base + eg;
    if (kk < cnt) {
        float4 v = *(const float4*)(hn2 + (size_t)a[kk] * EMB + d4 * 4);
        acc.x += v.x; acc.y += v.y; acc.z += v.z; acc.w += v.w;
    }
    kk += 8;
    if (kk < cnt) {
        float4 v = *(const float4*)(hn2 + (size_t)a[kk] * EMB + d4 * 4);
        acc.x += v.x; acc.y += v.y; acc.z += v.z; acc.w += v.w;
    }
    kk += 8;
    if (kk < cnt) {
        float4 v = *(const float4*)(hn2 + (size_t)a[kk] * EMB + d4 * 4);
        acc.x += v.x; acc.y += v.y; acc.z += v.z; acc.w += v.w;
    }
    float4 t = shfl_xor_f4(acc, 8);
    acc.x += t.x; acc.y += t.y; acc.z += t.z; acc.w += t.w;
    t = shfl_xor_f4(acc, 16);
    acc.x += t.x; acc.y += t.y; acc.z += t.z; acc.w += t.w;
    t = shfl_xor_f4(acc, 32);
    acc.x += t.x; acc.y += t.y; acc.z += t.z; acc.w += t.w;
    if (eg == 0) {
        float* dp = z + (size_t)node * EMB + d4 * 4;
        if (mode) {
            float4 old = *(float4*)dp;
            acc.x += old.x; acc.y += old.y; acc.z += old.z; acc.w += old.w;
        }
        *(float4*)dp = acc;
    }
}

// ---------------- agg2 final: last chunk + self + bias + scale --------------

__global__ void k_agg2z(const float* __restrict__ hn2, const int* __restrict__ adj,
                        const int* __restrict__ lo, const int* __restrict__ hi,
                        const float* __restrict__ dis, const float* __restrict__ b2,
                        float* __restrict__ z, int n) {
    int node = blockIdx.x * 4 + (threadIdx.x >> 6);
    if (node >= n) return;
    int lane = threadIdx.x & 63;
    int eg = lane >> 3;
    int d4 = lane & 7;
    int beg = lo[node];
    int cnt = hi[node] - beg;
    const int* a = adj + beg;
    float4 acc = make_float4(0.f, 0.f, 0.f, 0.f);
    int base = 0;
    for (; base + 24 <= cnt; base += 24) {
        int j0 = a[base + eg];
        int j1 = a[base + 8 + eg];
        int j2 = a[base + 16 + eg];
        float4 v0 = *(const float4*)(hn2 + (size_t)j0 * EMB + d4 * 4);
        float4 v1 = *(const float4*)(hn2 + (size_t)j1 * EMB + d4 * 4);
        float4 v2 = *(const float4*)(hn2 + (size_t)j2 * EMB + d4 * 4);
        acc.x += v0.x + v1.x + v2.x; acc.y += v0.y + v1.y + v2.y;
        acc.z += v0.z + v1.z + v2.z; acc.w += v0.w + v1.w + v2.w;
    }
    int kk = base + eg;
    if (kk < cnt) {
        float4 v = *(const float4*)(hn2 + (size_t)a[kk] * EMB + d4 * 4);
        acc.x += v.x; acc.y += v.y; acc.z += v.z; acc.w += v.w;
    }
    kk += 8;
    if (kk < cnt) {
        float4 v = *(const float4*)(hn2 + (size_t)a[kk] * EMB + d4 * 4);
        acc.x += v.x; acc.y += v.y; acc.z += v.z; acc.w += v.w;
    }
    kk += 8;
    if (kk < cnt) {
        float4 v = *(const float4*)(hn2 + (size_t)a[kk] * EMB + d4 * 4);
        acc.x += v.x; acc.y += v.y; acc.z += v.z; acc.w += v.w;
    }
    float4 t = shfl_xor_f4(acc, 8);
    acc.x += t.x; acc.y += t.y; acc.z += t.z; acc.w += t.w;
    t = shfl_xor_f4(acc, 16);
    acc.x += t.x; acc.y += t.y; acc.z += t.z; acc.w += t.w;
    t = shfl_xor_f4(acc, 32);
    acc.x += t.x; acc.y += t.y; acc.z += t.z; acc.w += t.w;
    if (eg == 0) {
        float4 part = *(float4*)(z + (size_t)node * EMB + d4 * 4);
        float4 self = *(const float4*)(hn2 + (size_t)node * EMB + d4 * 4);
        float4 bb = *(const float4*)(b2 + d4 * 4);
        float dn = dis[node];
        float4 o;
        o.x = dn * (acc.x + part.x + self.x) + bb.x;
        o.y = dn * (acc.y + part.y + self.y) + bb.y;
        o.z = dn * (acc.z + part.z + self.z) + bb.z;
        o.w = dn * (acc.w + part.w + self.w) + bb.w;
        *(float4*)(z + (size_t)node * EMB + d4 * 4) = o;
    }
}

// ---------------- pair head ----------------

__global__ void k_head(const float* __restrict__ z, const int* __restrict__ tg,
                       const float* __restrict__ Wo, const float* __restrict__ bo,
                       float* __restrict__ out, int btot) {
    int i = blockIdx.x * 256 + threadIdx.x;
    if (i >= btot) return;
    int t0 = tg[i], t1 = tg[btot + i];
    const float* z0 = z + (size_t)t0 * EMB;
    const float* z1 = z + (size_t)t1 * EMB;
    float acc = 0.f;
#pragma unroll
    for (int g = 0; g < EMB; ++g) acc += z0[g] * z1[g] * Wo[g];
    out[i] = acc + bo[0];
}

// ---------------- launch ----------------

extern "C" void kernel_launch(void* const* d_in, const int* in_sizes, int n_in,
                              void* d_out, int out_size, void* d_ws, size_t ws_size,
                              hipStream_t stream) {
    const float* x  = (const float*)d_in[0];
    const int*   ei = (const int*)d_in[1];
    const int*   tg = (const int*)d_in[2];
    const float* W1 = (const float*)d_in[3];
    const float* b1 = (const float*)d_in[4];
    const float* W2 = (const float*)d_in[5];
    const float* b2 = (const float*)d_in[6];
    const float* Wo = (const float*)d_in[7];
    const float* bo = (const float*)d_in[8];
    float* out = (float*)d_out;

    int n = in_sizes[0] / IN_DIM;
    int e = in_sizes[1] / 2;
    int b = in_sizes[2] / 2;
    const int* src = ei;
    const int* dst = ei + e;

    char* ws = (char*)d_ws;
    size_t off = 0;
    auto alloc = [&](size_t bytes) -> char* {
        char* p = ws + off;
        off += (bytes + 255) & ~(size_t)255;
        return p;
    };
    int*   deg       = (int*)alloc((size_t)n * 4);
    int*   row_ptr   = (int*)alloc((size_t)n * 4);
    int*   write_ptr = (int*)alloc((size_t)n * 4);
    int*   m1        = (int*)alloc((size_t)n * 4);
    int*   m2        = (int*)alloc((size_t)n * 4);
    int*   mend      = (int*)alloc((size_t)n * 4);
    int*   blksums   = (int*)alloc(1024 * 4);
    int*   blkoffs   = (int*)alloc(1024 * 4);
    float* dis       = (float*)alloc((size_t)n * 4);
    int*   adj       = (int*)alloc((size_t)e * 4);
    float* xn        = (float*)alloc((size_t)n * XPAD * 4);
    float* agg       = (float*)alloc((size_t)n * XPAD * 4);
    float* bufA      = (float*)alloc((size_t)n * EMB * 4);   // hn2
    float* bufB      = (float*)alloc((size_t)n * EMB * 4);   // z
    int*   gcnt      = (int*)alloc(1024);
    int*   gbase     = (int*)alloc(1024);

    int Pp = (n + 511) >> PSHIFT;
    int meanb = (Pp > 0) ? (e / Pp) : e;
    int cap = meanb + meanb / 16 + 1024;
    size_t bucket_bytes = (size_t)Pp * cap * 8;
    bool use_buckets = (Pp <= PMAX) && ((off + bucket_bytes + 256) <= ws_size);
    u64* gbuf = (u64*)alloc(bucket_bytes);

    int nb1024 = (n + 1023) / 1024;
    int nrange = (n + NGROUP - 1) / NGROUP;
    int c1 = (n + 2) / 3;
    int c2 = min(2 * c1, n);
    int nblk4 = (n + 3) / 4;

    k_init<<<(n + 255) / 256, 256, 0, stream>>>(deg, gcnt, n);

    if (use_buckets) {
        k_part<<<512, 256, 0, stream>>>(src, dst, gcnt, gbuf, e, Pp, cap);
        k_gscan<<<1, 256, 0, stream>>>(gcnt, gbase, Pp);
        k_build3<<<Pp, 512, 0, stream>>>(gbuf, gcnt, gbase, deg, dis, row_ptr,
                                         m1, m2, mend, adj, cap, n, c1, c2);
    } else {
        k_count_part<<<2048, 256, 0, stream>>>(dst, deg, e, nrange, n);
        k_dis<<<(n + 255) / 256, 256, 0, stream>>>(deg, dis, n);
        k_scanA<<<nb1024, 1024, 0, stream>>>(deg, row_ptr, blksums, n);
        k_scanB<<<1, 1024, 0, stream>>>(blksums, blkoffs, nb1024);
        k_scanC<<<nb1024, 1024, 0, stream>>>(row_ptr, blkoffs, write_ptr, n);
        k_fill_part<<<2048, 256, 0, stream>>>(src, dst, write_ptr, adj, e, nrange, n);
        k_mend<<<(n + 255) / 256, 256, 0, stream>>>(row_ptr, deg, mend, n);
    }

    k_xn<<<((size_t)n * 5 + 255) / 256, 256, 0, stream>>>(x, dis, xn, n);

    if (use_buckets) {
        // layer 1: 3 src-chunk phases (each xn chunk ~2.7MB -> L2-resident)
        k_agg1p<<<nblk4, 256, 0, stream>>>(xn, adj, row_ptr, m1, agg, n, 0);
        k_agg1p<<<nblk4, 256, 0, stream>>>(xn, adj, m1, m2, agg, n, 1);
        k_agg1z<<<nblk4, 256, 0, stream>>>(xn, adj, m2, mend, agg, dis, W1, b1, W2, bufA, n);
        // layer 2: 3 src-chunk phases over hn2
        k_agg2p<<<nblk4, 256, 0, stream>>>(bufA, adj, row_ptr, m1, bufB, n, 0);
        k_agg2p<<<nblk4, 256, 0, stream>>>(bufA, adj, m1, m2, bufB, n, 1);
        k_agg2z<<<nblk4, 256, 0, stream>>>(bufA, adj, m2, mend, dis, b2, bufB, n);
    } else {
        k_agg1p<<<nblk4, 256, 0, stream>>>(xn, adj, row_ptr, mend, agg, n, 0);
        k_agg1z<<<nblk4, 256, 0, stream>>>(xn, adj, mend, mend, agg, dis, W1, b1, W2, bufA, n);
        k_agg2p<<<nblk4, 256, 0, stream>>>(bufA, adj, row_ptr, mend, bufB, n, 0);
        k_agg2z<<<nblk4, 256, 0, stream>>>(bufA, adj, mend, mend, dis, b2, bufB, n);
    }

    k_head<<<(b + 255) / 256, 256, 0, stream>>>(bufB, tg, Wo, bo, out, b);
}

// Round 10
// 243.313 us; speedup vs baseline: 1.4798x; 1.4798x over previous
//
#include <hip/hip_runtime.h>

#define IN_DIM 18
#define HID 64
#define EMB 32
#define NGROUP 8    // legacy fallback partitioning
#define PSHIFT 9    // 512 nodes per partition
#define PMAX 200    // LDS arrays sized for <=200 partitions (N<=102400)
#define BCAP 40     // k_part per-tile LDS bin capacity (mean ~21 @ TILE 4096)
#define TILE 4096
#define SCAP 16896  // k_build LDS pair-staging capacity (mean ~16384)

typedef int vint4 __attribute__((ext_vector_type(4)));
typedef unsigned long long u64;

__device__ inline float4 shfl_f4(float4 v, int srcLane) {
    float4 r;
    r.x = __shfl(v.x, srcLane);
    r.y = __shfl(v.y, srcLane);
    r.z = __shfl(v.z, srcLane);
    r.w = __shfl(v.w, srcLane);
    return r;
}

__device__ inline float4 shfl_xor_f4(float4 v, int m) {
    v.x = __shfl_xor(v.x, m);
    v.y = __shfl_xor(v.y, m);
    v.z = __shfl_xor(v.z, m);
    v.w = __shfl_xor(v.w, m);
    return v;
}

// ---------------- init ----------------

__global__ void k_init(int* __restrict__ deg, int* __restrict__ gcnt, int n) {
    int i = blockIdx.x * 256 + threadIdx.x;
    if (i < n) deg[i] = 1;          // legacy path
    if (i < 256) gcnt[i] = 0;
}

// ---------------- bucketing: (dst,src) -> P dst-partition buckets ----------
// pair packed as u64: (src<<32) | dst

__global__ void k_part(const int* __restrict__ src, const int* __restrict__ dst,
                       int* __restrict__ gcnt, u64* __restrict__ gbuf,
                       int e, int Pp, int cap) {
    __shared__ u64 sbuf[PMAX][BCAP];
    __shared__ int scnt[PMAX];
    __shared__ int sbase[PMAX];
    int tid = threadIdx.x;
    int ntile = (e + TILE - 1) / TILE;
    for (int tile = blockIdx.x; tile < ntile; tile += gridDim.x) {
        for (int p = tid; p < Pp; p += 256) scnt[p] = 0;
        __syncthreads();
#pragma unroll
        for (int r = 0; r < TILE / 1024; ++r) {
            int i = tile * TILE + (r * 256 + tid) * 4;
            if (i + 4 <= e) {
                vint4 s4 = __builtin_nontemporal_load((const vint4*)(src + i));
                vint4 d4 = __builtin_nontemporal_load((const vint4*)(dst + i));
#pragma unroll
                for (int k = 0; k < 4; ++k) {
                    int d = d4[k];
                    int p = d >> PSHIFT;
                    u64 pr = ((u64)(unsigned)s4[k] << 32) | (unsigned)d;
                    int pos = atomicAdd(&scnt[p], 1);
                    if (pos < BCAP) sbuf[p][pos] = pr;
                    else {
                        int gp = atomicAdd(&gcnt[p], 1);
                        __builtin_nontemporal_store(pr, &gbuf[(size_t)p * cap + gp]);
                    }
                }
            } else if (i < e) {
                for (int k = i; k < e; ++k) {
                    int d = dst[k];
                    int p = d >> PSHIFT;
                    u64 pr = ((u64)(unsigned)src[k] << 32) | (unsigned)d;
                    int pos = atomicAdd(&scnt[p], 1);
                    if (pos < BCAP) sbuf[p][pos] = pr;
                    else {
                        int gp = atomicAdd(&gcnt[p], 1);
                        __builtin_nontemporal_store(pr, &gbuf[(size_t)p * cap + gp]);
                    }
                }
            }
        }
        __syncthreads();
        for (int p = tid; p < Pp; p += 256)
            sbase[p] = atomicAdd(&gcnt[p], min(scnt[p], BCAP));
        __syncthreads();
        int wid = tid >> 6, lane = tid & 63;
        for (int p = wid; p < Pp; p += 4) {
            int c = min(scnt[p], BCAP);
            int b = sbase[p];
            for (int k = lane; k < c; k += 64)
                __builtin_nontemporal_store(sbuf[p][k], &gbuf[(size_t)p * cap + b + k]);
        }
        __syncthreads();
    }
}

// ---------------- tiny exclusive scan of bucket counts ----------------

__global__ void k_gscan(const int* __restrict__ gcnt, int* __restrict__ gbase, int Pp) {
    __shared__ int s[256];
    int t = threadIdx.x;
    int v = (t < Pp) ? gcnt[t] : 0;
    s[t] = v;
    __syncthreads();
    for (int off = 1; off < 256; off <<= 1) {
        int u = (t >= off) ? s[t - off] : 0;
        __syncthreads();
        s[t] += u;
        __syncthreads();
    }
    if (t < Pp) gbase[t] = s[t] - v;
}

// ---------------- per-partition build: deg/dis/row_ptr/adj (512 thr) --------

__global__ void k_build(const u64* __restrict__ gbuf, const int* __restrict__ gcnt,
                        const int* __restrict__ gbase, int* __restrict__ deg,
                        float* __restrict__ dis, int* __restrict__ row_ptr,
                        int* __restrict__ adj, int cap, int n) {
    __shared__ u64 spairs[SCAP];
    __shared__ int sdeg[512];
    __shared__ int sexcl[512];
    __shared__ int swp[512];
    __shared__ int sscan[512];
    int p = blockIdx.x;
    int tid = threadIdx.x;
    int lo = p << PSHIFT;
    int nn = min(n - lo, 512);
    int cnt = gcnt[p];
    int base = gbase[p];
    const u64* buf = gbuf + (size_t)p * cap;

    sdeg[tid] = 0;
    int scap = min(cnt, SCAP);
    for (int k = tid; k < scap; k += 512)
        spairs[k] = __builtin_nontemporal_load(&buf[k]);
    __syncthreads();
    for (int k = tid; k < cnt; k += 512) {
        u64 pr = (k < SCAP) ? spairs[k] : __builtin_nontemporal_load(&buf[k]);
        atomicAdd(&sdeg[(int)(pr & 0xffffffffu) - lo], 1);
    }
    __syncthreads();
    int v = sdeg[tid];
    sscan[tid] = v;
    __syncthreads();
    for (int off = 1; off < 512; off <<= 1) {
        int u = (tid >= off) ? sscan[tid - off] : 0;
        __syncthreads();
        sscan[tid] += u;
        __syncthreads();
    }
    sexcl[tid] = sscan[tid] - v;
    swp[tid] = 0;
    __syncthreads();
    if (tid < nn) {
        int dg = sdeg[tid] + 1;
        deg[lo + tid] = dg;
        dis[lo + tid] = rsqrtf((float)dg);
        row_ptr[lo + tid] = base + sexcl[tid];
    }
    for (int k = tid; k < cnt; k += 512) {
        u64 pr = (k < SCAP) ? spairs[k] : __builtin_nontemporal_load(&buf[k]);
        int dl = (int)(pr & 0xffffffffu) - lo;
        int slot = sexcl[dl] + atomicAdd(&swp[dl], 1);
        adj[base + slot] = (int)(pr >> 32);
    }
}

// ---------------- legacy fallback ----------------

__global__ void k_count_part(const int* __restrict__ dst, int* __restrict__ deg,
                             int e, int nrange, int n) {
    int g  = blockIdx.x & (NGROUP - 1);
    int lo = g * nrange;
    int hi = min(n, lo + nrange);
    int bid  = blockIdx.x >> 3;
    int nblk = gridDim.x >> 3;
    int i0   = (bid * 256 + threadIdx.x) * 4;
    int step = nblk * 256 * 4;
    for (int i = i0; i < e; i += step) {
        if (i + 4 <= e) {
            int4 d4 = *(const int4*)(dst + i);
            if (d4.x >= lo && d4.x < hi) atomicAdd(&deg[d4.x], 1);
            if (d4.y >= lo && d4.y < hi) atomicAdd(&deg[d4.y], 1);
            if (d4.z >= lo && d4.z < hi) atomicAdd(&deg[d4.z], 1);
            if (d4.w >= lo && d4.w < hi) atomicAdd(&deg[d4.w], 1);
        } else {
            for (int k = i; k < e; ++k) {
                int d = dst[k];
                if (d >= lo && d < hi) atomicAdd(&deg[d], 1);
            }
        }
    }
}

__global__ void k_dis(const int* __restrict__ deg, float* __restrict__ dis, int n) {
    int i = blockIdx.x * 256 + threadIdx.x;
    if (i < n) dis[i] = rsqrtf((float)deg[i]);
}

__global__ void k_scanA(const int* __restrict__ deg, int* __restrict__ row_ptr,
                        int* __restrict__ blksums, int n) {
    __shared__ int s[1024];
    int tid = threadIdx.x;
    int i = blockIdx.x * 1024 + tid;
    int v = (i < n) ? (deg[i] - 1) : 0;
    s[tid] = v;
    __syncthreads();
    for (int off = 1; off < 1024; off <<= 1) {
        int t = (tid >= off) ? s[tid - off] : 0;
        __syncthreads();
        s[tid] += t;
        __syncthreads();
    }
    if (i < n) row_ptr[i] = s[tid] - v;
    if (tid == 1023) blksums[blockIdx.x] = s[1023];
}

__global__ void k_scanB(const int* __restrict__ blksums, int* __restrict__ blkoffs, int nb) {
    __shared__ int s[1024];
    int tid = threadIdx.x;
    int v = (tid < nb) ? blksums[tid] : 0;
    s[tid] = v;
    __syncthreads();
    for (int off = 1; off < 1024; off <<= 1) {
        int t = (tid >= off) ? s[tid - off] : 0;
        __syncthreads();
        s[tid] += t;
        __syncthreads();
    }
    if (tid < nb) blkoffs[tid] = s[tid] - v;
}

__global__ void k_scanC(int* __restrict__ row_ptr, const int* __restrict__ blkoffs,
                        int* __restrict__ write_ptr, int n) {
    int i = blockIdx.x * 1024 + threadIdx.x;
    if (i < n) {
        int r = row_ptr[i] + blkoffs[blockIdx.x];
        row_ptr[i] = r;
        write_ptr[i] = r;
    }
}

__global__ void k_fill_part(const int* __restrict__ src, const int* __restrict__ dst,
                            int* __restrict__ write_ptr, int* __restrict__ adj,
                            int e, int nrange, int n) {
    int g  = blockIdx.x & (NGROUP - 1);
    int lo = g * nrange;
    int hi = min(n, lo + nrange);
    int bid  = blockIdx.x >> 3;
    int nblk = gridDim.x >> 3;
    int i0   = (bid * 256 + threadIdx.x) * 4;
    int step = nblk * 256 * 4;
    for (int i = i0; i < e; i += step) {
        if (i + 4 <= e) {
            int4 d4 = *(const int4*)(dst + i);
            if (d4.x >= lo && d4.x < hi) { int slot = atomicAdd(&write_ptr[d4.x], 1); adj[slot] = src[i];     }
            if (d4.y >= lo && d4.y < hi) { int slot = atomicAdd(&write_ptr[d4.y], 1); adj[slot] = src[i + 1]; }
            if (d4.z >= lo && d4.z < hi) { int slot = atomicAdd(&write_ptr[d4.z], 1); adj[slot] = src[i + 2]; }
            if (d4.w >= lo && d4.w < hi) { int slot = atomicAdd(&write_ptr[d4.w], 1); adj[slot] = src[i + 3]; }
        } else {
            for (int k = i; k < e; ++k) {
                int d = dst[k];
                if (d >= lo && d < hi) { int slot = atomicAdd(&write_ptr[d], 1); adj[slot] = src[k]; }
            }
        }
    }
}

// ---------------- xn split tables: xnA[n][16] (64B rows), xnB[n][4] ----------

__global__ void k_xn(const float* __restrict__ x, const float* __restrict__ dis,
                     float* __restrict__ xnA, float* __restrict__ xnB, int n) {
    int gid = blockIdx.x * 256 + threadIdx.x;
    if (gid >= n * 5) return;
    int i = gid / 5, s = gid - (gid / 5) * 5;
    float dn = dis[i];
    const float* xr = x + (size_t)i * IN_DIM;
    float4 v;
    int k = s * 4;
    v.x = (k + 0 < IN_DIM) ? xr[k + 0] * dn : 0.f;
    v.y = (k + 1 < IN_DIM) ? xr[k + 1] * dn : 0.f;
    v.z = (k + 2 < IN_DIM) ? xr[k + 2] * dn : 0.f;
    v.w = (k + 3 < IN_DIM) ? xr[k + 3] * dn : 0.f;
    if (s < 4) *(float4*)(xnA + (size_t)i * 16 + k) = v;
    else       *(float4*)(xnB + (size_t)i * 4) = v;
}

// ---------------- fused layer 1+2a: gather xnA/xnB + W1 + relu + W2 ---------
// One wave per node. 12 edge-groups x 5 lanes (lanes 0-3: one aligned 64B
// line from xnA; lane 4: 16B from L2-resident xnB), x2 unroll = 24 gathers
// in flight. Shuffle tree 12->1, LDS broadcast, W1 dot + relu, W2 dot.

__global__ void k_agg1f(const float* __restrict__ xnA, const float* __restrict__ xnB,
                        const int* __restrict__ row_ptr, const int* __restrict__ deg,
                        const int* __restrict__ adj, const float* __restrict__ dis,
                        const float* __restrict__ W1, const float* __restrict__ b1,
                        const float* __restrict__ W2, float* __restrict__ hn2, int n) {
    __shared__ float sw[IN_DIM * HID];
    __shared__ float sw2[HID * EMB];
    __shared__ float sb[HID];
    __shared__ __align__(16) float sagg[4][20];
    __shared__ float sh[4][HID];
    int tid = threadIdx.x;
    for (int t = tid; t < IN_DIM * HID; t += 256) sw[t] = W1[t];
    for (int t = tid; t < HID * EMB; t += 256) sw2[t] = W2[t];
    if (tid < HID) sb[tid] = b1[tid];
    __syncthreads();
    int node = blockIdx.x * 4 + (tid >> 6);
    if (node >= n) return;
    int lane = tid & 63;
    int wv = tid >> 6;
    int eg = lane / 5;               // 0..12 (lanes 60-63 inactive)
    int sl = lane - eg * 5;          // 0..3 -> xnA slot, 4 -> xnB
    bool act = eg < 12;
    int beg = row_ptr[node];
    int cnt = deg[node] - 1;
    const int* a = adj + beg;
    float4 acc = make_float4(0.f, 0.f, 0.f, 0.f);
    int base = 0;
    for (; base + 24 <= cnt; base += 24) {
        if (act) {
            int j0 = a[base + eg];
            int j1 = a[base + 12 + eg];
            const float* p0 = (sl < 4) ? (xnA + (size_t)j0 * 16 + sl * 4) : (xnB + (size_t)j0 * 4);
            const float* p1 = (sl < 4) ? (xnA + (size_t)j1 * 16 + sl * 4) : (xnB + (size_t)j1 * 4);
            float4 v0 = *(const float4*)p0;
            float4 v1 = *(const float4*)p1;
            acc.x += v0.x + v1.x; acc.y += v0.y + v1.y;
            acc.z += v0.z + v1.z; acc.w += v0.w + v1.w;
        }
    }
    if (act && base + eg < cnt) {
        int j = a[base + eg];
        const float* p = (sl < 4) ? (xnA + (size_t)j * 16 + sl * 4) : (xnB + (size_t)j * 4);
        float4 v = *(const float4*)p;
        acc.x += v.x; acc.y += v.y; acc.z += v.z; acc.w += v.w;
    }
    if (act && base + 12 + eg < cnt) {
        int j = a[base + 12 + eg];
        const float* p = (sl < 4) ? (xnA + (size_t)j * 16 + sl * 4) : (xnB + (size_t)j * 4);
        float4 v = *(const float4*)p;
        acc.x += v.x; acc.y += v.y; acc.z += v.z; acc.w += v.w;
    }
    // reduce 12 groups -> group 0
    float4 t = shfl_f4(acc, lane + 30);
    if (lane < 30) { acc.x += t.x; acc.y += t.y; acc.z += t.z; acc.w += t.w; }
    t = shfl_f4(acc, lane + 15);
    if (lane < 15) { acc.x += t.x; acc.y += t.y; acc.z += t.z; acc.w += t.w; }
    t = shfl_f4(acc, lane + 10);
    if (lane < 5) { acc.x += t.x; acc.y += t.y; acc.z += t.z; acc.w += t.w; }
    t = shfl_f4(acc, lane + 5);
    if (lane < 5) { acc.x += t.x; acc.y += t.y; acc.z += t.z; acc.w += t.w; }
    float dn = dis[node];
    if (lane < 5) {
        const float* ps = (lane < 4) ? (xnA + (size_t)node * 16 + lane * 4) : (xnB + (size_t)node * 4);
        float4 s4v = *(const float4*)ps;
        acc.x += s4v.x; acc.y += s4v.y; acc.z += s4v.z; acc.w += s4v.w;
        *(float4*)&sagg[wv][lane * 4] = acc;   // same-wave LDS
    }
    float s = 0.f;
#pragma unroll
    for (int k = 0; k < IN_DIM; ++k) s += sagg[wv][k] * sw[k * HID + lane];
    float hv = dn * s + sb[lane];
    sh[wv][lane] = hv > 0.f ? hv : 0.f;        // h row stays in LDS
    int g = lane & 31, half = lane >> 5;
    float s2 = 0.f;
#pragma unroll
    for (int k = 0; k < 32; ++k) s2 += sh[wv][half * 32 + k] * sw2[(half * 32 + k) * EMB + g];
    s2 += __shfl_xor(s2, 32);
    if (half == 0) hn2[(size_t)node * EMB + g] = dn * s2;
}

// ---------------- layer-2 aggregation (float4 per lane, x3 unroll) ----------

__global__ void k_agg2(const float* __restrict__ hn2, const int* __restrict__ row_ptr,
                       const int* __restrict__ deg, const int* __restrict__ adj,
                       const float* __restrict__ dis, const float* __restrict__ b2,
                       float* __restrict__ z, int n) {
    int node = blockIdx.x * 4 + (threadIdx.x >> 6);
    if (node >= n) return;
    int lane = threadIdx.x & 63;
    int eg = lane >> 3;
    int d4 = lane & 7;
    int beg = row_ptr[node];
    int cnt = deg[node] - 1;
    const int* a = adj + beg;
    float4 acc = make_float4(0.f, 0.f, 0.f, 0.f);
    int base = 0;
    for (; base + 24 <= cnt; base += 24) {
        int j0 = a[base + eg];
        int j1 = a[base + 8 + eg];
        int j2 = a[base + 16 + eg];
        float4 v0 = *(const float4*)(hn2 + (size_t)j0 * EMB + d4 * 4);
        float4 v1 = *(const float4*)(hn2 + (size_t)j1 * EMB + d4 * 4);
        float4 v2 = *(const float4*)(hn2 + (size_t)j2 * EMB + d4 * 4);
        acc.x += v0.x + v1.x + v2.x; acc.y += v0.y + v1.y + v2.y;
        acc.z += v0.z + v1.z + v2.z; acc.w += v0.w + v1.w + v2.w;
    }
    int kk = base + eg;
    if (kk < cnt) {
        float4 v = *(const float4*)(hn2 + (size_t)a[kk] * EMB + d4 * 4);
        acc.x += v.x; acc.y += v.y; acc.z += v.z; acc.w += v.w;
    }
    kk += 8;
    if (kk < cnt) {
        float4 v = *(const float4*)(hn2 + (size_t)a[kk] * EMB + d4 * 4);
        acc.x += v.x; acc.y += v.y; acc.z += v.z; acc.w += v.w;
    }
    kk += 8;
    if (kk < cnt) {
        float4 v = *(const float4*)(hn2 + (size_t)a[kk] * EMB + d4 * 4);
        acc.x += v.x; acc.y += v.y; acc.z += v.z; acc.w += v.w;
    }
    float4 t = shfl_xor_f4(acc, 8);
    acc.x += t.x; acc.y += t.y; acc.z += t.z; acc.w += t.w;
    t = shfl_xor_f4(acc, 16);
    acc.x += t.x; acc.y += t.y; acc.z += t.z; acc.w += t.w;
    t = shfl_xor_f4(acc, 32);
    acc.x += t.x; acc.y += t.y; acc.z += t.z; acc.w += t.w;
    if (eg == 0) {
        float4 self = *(const float4*)(hn2 + (size_t)node * EMB + d4 * 4);
        float4 bb = *(const float4*)(b2 + d4 * 4);
        float dn = dis[node];
        float4 o;
        o.x = dn * (acc.x + self.x) + bb.x;
        o.y = dn * (acc.y + self.y) + bb.y;
        o.z = dn * (acc.z + self.z) + bb.z;
        o.w = dn * (acc.w + self.w) + bb.w;
        *(float4*)(z + (size_t)node * EMB + d4 * 4) = o;
    }
}

// ---------------- pair head ----------------

__global__ void k_head(const float* __restrict__ z, const int* __restrict__ tg,
                       const float* __restrict__ Wo, const float* __restrict__ bo,
                       float* __restrict__ out, int btot) {
    int i = blockIdx.x * 256 + threadIdx.x;
    if (i >= btot) return;
    int t0 = tg[i], t1 = tg[btot + i];
    const float* z0 = z + (size_t)t0 * EMB;
    const float* z1 = z + (size_t)t1 * EMB;
    float acc = 0.f;
#pragma unroll
    for (int g = 0; g < EMB; ++g) acc += z0[g] * z1[g] * Wo[g];
    out[i] = acc + bo[0];
}

// ---------------- launch ----------------

extern "C" void kernel_launch(void* const* d_in, const int* in_sizes, int n_in,
                              void* d_out, int out_size, void* d_ws, size_t ws_size,
                              hipStream_t stream) {
    const float* x  = (const float*)d_in[0];
    const int*   ei = (const int*)d_in[1];
    const int*   tg = (const int*)d_in[2];
    const float* W1 = (const float*)d_in[3];
    const float* b1 = (const float*)d_in[4];
    const float* W2 = (const float*)d_in[5];
    const float* b2 = (const float*)d_in[6];
    const float* Wo = (const float*)d_in[7];
    const float* bo = (const float*)d_in[8];
    float* out = (float*)d_out;

    int n = in_sizes[0] / IN_DIM;
    int e = in_sizes[1] / 2;
    int b = in_sizes[2] / 2;
    const int* src = ei;
    const int* dst = ei + e;

    char* ws = (char*)d_ws;
    size_t off = 0;
    auto alloc = [&](size_t bytes) -> char* {
        char* p = ws + off;
        off += (bytes + 255) & ~(size_t)255;
        return p;
    };
    int*   deg       = (int*)alloc((size_t)n * 4);
    int*   row_ptr   = (int*)alloc((size_t)n * 4);
    int*   write_ptr = (int*)alloc((size_t)n * 4);
    int*   blksums   = (int*)alloc(1024 * 4);
    int*   blkoffs   = (int*)alloc(1024 * 4);
    float* dis       = (float*)alloc((size_t)n * 4);
    int*   adj       = (int*)alloc((size_t)e * 4);
    float* xnA       = (float*)alloc((size_t)n * 16 * 4);    // 64B rows
    float* xnB       = (float*)alloc((size_t)n * 4 * 4);     // 16B rows
    float* bufA      = (float*)alloc((size_t)n * EMB * 4);   // hn2
    float* bufB      = (float*)alloc((size_t)n * EMB * 4);   // z
    int*   gcnt      = (int*)alloc(1024);
    int*   gbase     = (int*)alloc(1024);

    int Pp = (n + 511) >> PSHIFT;
    int meanb = (Pp > 0) ? (e / Pp) : e;
    int cap = meanb + meanb / 16 + 1024;
    size_t bucket_bytes = (size_t)Pp * cap * 8;
    bool use_buckets = (Pp <= PMAX) && ((off + bucket_bytes + 256) <= ws_size);
    u64* gbuf = (u64*)alloc(bucket_bytes);

    int nb1024 = (n + 1023) / 1024;
    int nrange = (n + NGROUP - 1) / NGROUP;

    k_init<<<(n + 255) / 256, 256, 0, stream>>>(deg, gcnt, n);

    if (use_buckets) {
        k_part<<<512, 256, 0, stream>>>(src, dst, gcnt, gbuf, e, Pp, cap);
        k_gscan<<<1, 256, 0, stream>>>(gcnt, gbase, Pp);
        k_build<<<Pp, 512, 0, stream>>>(gbuf, gcnt, gbase, deg, dis, row_ptr, adj, cap, n);
    } else {
        k_count_part<<<2048, 256, 0, stream>>>(dst, deg, e, nrange, n);
        k_dis<<<(n + 255) / 256, 256, 0, stream>>>(deg, dis, n);
        k_scanA<<<nb1024, 1024, 0, stream>>>(deg, row_ptr, blksums, n);
        k_scanB<<<1, 1024, 0, stream>>>(blksums, blkoffs, nb1024);
        k_scanC<<<nb1024, 1024, 0, stream>>>(row_ptr, blkoffs, write_ptr, n);
        k_fill_part<<<2048, 256, 0, stream>>>(src, dst, write_ptr, adj, e, nrange, n);
    }

    k_xn<<<((size_t)n * 5 + 255) / 256, 256, 0, stream>>>(x, dis, xnA, xnB, n);
    k_agg1f<<<(n + 3) / 4, 256, 0, stream>>>(xnA, xnB, row_ptr, deg, adj, dis, W1, b1, W2, bufA, n);
    k_agg2<<<(n + 3) / 4, 256, 0, stream>>>(bufA, row_ptr, deg, adj, dis, b2, bufB, n);

    k_head<<<(b + 255) / 256, 256, 0, stream>>>(bufB, tg, Wo, bo, out, b);
}